// Round 1
// baseline (232.693 us; speedup 1.0000x reference)
//
#include <hip/hip_runtime.h>
#include <math.h>

// LayerNorm(Re(FFT(x, axis=-1))), x: (B=4, N=4096, C=2048) fp32.
// One 256-thread block per PAIR of rows: z = x_even + i*x_odd.
// Register-resident Stockham FFT: radix-8 stages (S=1,8,64) + final radix-4
// (S=512, twiddle-free, in registers). LDS used only for the 3 inter-stage
// transposes + 1 untangle exchange, in a single padded buffer
// phys(i) = i + (i>>3)  (18.4 KB/block -> 8 blocks/CU, 100% wave occupancy).

#define TPB 256
#define CD  2048

__device__ __forceinline__ float2 cadd(float2 a, float2 b){ return make_float2(a.x+b.x, a.y+b.y); }
__device__ __forceinline__ float2 csub(float2 a, float2 b){ return make_float2(a.x-b.x, a.y-b.y); }

// y_r = sum_k z_k * exp(-2*pi*i*k*r/8), natural output order.
__device__ __forceinline__ void dft8(const float2* z, float2* y)
{
    const float C8 = 0.70710678118654752440f;  // sqrt(2)/2
    float2 a0=cadd(z[0],z[4]), a1=cadd(z[1],z[5]), a2=cadd(z[2],z[6]), a3=cadd(z[3],z[7]);
    float2 b0=csub(z[0],z[4]), b1=csub(z[1],z[5]), b2=csub(z[2],z[6]), b3=csub(z[3],z[7]);
    float2 t1=make_float2(C8*(b1.x+b1.y), C8*(b1.y-b1.x));     // b1 * w8^1
    float2 t2=make_float2(b2.y, -b2.x);                        // b2 * w8^2 = -i
    float2 t3=make_float2(C8*(b3.y-b3.x), -C8*(b3.x+b3.y));    // b3 * w8^3
    {   // even outputs = DFT4(a0..a3)
        float pr=a0.x+a2.x, pi=a0.y+a2.y, mr=a0.x-a2.x, mi=a0.y-a2.y;
        float qr=a1.x+a3.x, qi=a1.y+a3.y, nr=a1.x-a3.x, ni=a1.y-a3.y;
        y[0]=make_float2(pr+qr,pi+qi); y[2]=make_float2(mr+ni,mi-nr);
        y[4]=make_float2(pr-qr,pi-qi); y[6]=make_float2(mr-ni,mi+nr);
    }
    {   // odd outputs = DFT4(b0,t1,t2,t3)
        float pr=b0.x+t2.x, pi=b0.y+t2.y, mr=b0.x-t2.x, mi=b0.y-t2.y;
        float qr=t1.x+t3.x, qi=t1.y+t3.y, nr=t1.x-t3.x, ni=t1.y-t3.y;
        y[1]=make_float2(pr+qr,pi+qi); y[3]=make_float2(mr+ni,mi-nr);
        y[5]=make_float2(pr-qr,pi-qi); y[7]=make_float2(mr-ni,mi+nr);
    }
}

// Stockham store with twiddles W^(p*r), W = exp(-2*pi*i/(2048/S_)).
// Lw points at phys(base) for this thread; OFFM = physical stride of r-step.
template<int S_, int OFFM>
__device__ __forceinline__ void r8_store(float2* Lw, const float2* y, int p)
{
    Lw[0] = y[0];
    if (S_ == 64 && p == 0) {       // wave 0 of stage C: all twiddles are 1
#pragma unroll
        for (int r = 1; r < 8; ++r) Lw[OFFM*r] = y[r];
        return;
    }
    const float th = -6.28318530717958647692f * ((float)S_ / 2048.0f);
    float s1, c1;
    __sincosf(th * (float)p, &s1, &c1);
    float cr=c1, sr=s1;
    Lw[OFFM] = make_float2(c1*y[1].x - s1*y[1].y, c1*y[1].y + s1*y[1].x);
#pragma unroll
    for (int r = 2; r < 8; ++r) {
        float cn = cr*c1 - sr*s1, sn = sr*c1 + cr*s1;   // (c1+i*s1)^r
        cr=cn; sr=sn;
        Lw[OFFM*r] = make_float2(cr*y[r].x - sr*y[r].y, cr*y[r].y + sr*y[r].x);
    }
}

__global__ __launch_bounds__(TPB, 8) void fourier_ln_kernel(
    const float* __restrict__ x,
    const float* __restrict__ gamma,
    const float* __restrict__ beta,
    float* __restrict__ out)
{
    __shared__ float2 L[2304];    // 2048 logical + 256 pad: phys(i) = i + (i>>3)
    __shared__ float rmem[20];    // cross-wave reduction scratch

    const int t  = threadIdx.x;
    const int t8 = t >> 3;
    const long long row0 = 2LL * (long long)blockIdx.x;
    const float* __restrict__ x0 = x + row0 * CD;
    const float* __restrict__ x1 = x0 + CD;

    // Direct strided-coalesced loads: element t+256r of z = x0 + i*x1.
    float2 z[8], y[8];
#pragma unroll
    for (int r = 0; r < 8; ++r) {
        const int k = t + 256*r;
        z[r] = make_float2(x0[k], x1[k]);
    }

    float2* const Lr = L + (t + t8);   // logical t+256r -> phys base + 288r

    // Stage A: radix-8, S=1 (q=0, p=t). logical 8t+r -> phys 9t+r.
    dft8(z, y);
    r8_store<1, 1>(L + 9*t, y, t);
    __syncthreads();
#pragma unroll
    for (int r = 0; r < 8; ++r) z[r] = Lr[288*r];
    __syncthreads();

    // Stage B: radix-8, S=8 (q=t&7, p=t>>3). logical q+64p+8r -> phys q+72p+9r.
    dft8(z, y);
    r8_store<8, 9>(L + ((t & 7) + 72*t8), y, t8);
    __syncthreads();
#pragma unroll
    for (int r = 0; r < 8; ++r) z[r] = Lr[288*r];
    __syncthreads();

    // Stage C: radix-8, S=64 (q=t&63, p=t>>6). logical q+512p+64r -> phys q+(q>>3)+576p+72r.
    dft8(z, y);
    {
        const int q = t & 63, p = t >> 6;
        r8_store<64, 72>(L + (q + (q >> 3) + 576*p), y, p);
    }
    __syncthreads();
#pragma unroll
    for (int r = 0; r < 8; ++r) z[r] = Lr[288*r];
    __syncthreads();

    // Stage D: radix-4, S=512, p=0 (twiddle-free), entirely in registers.
    // Butterfly b=t uses z[0],z[2],z[4],z[6] -> Z at k=t+512m (j even);
    // butterfly b=t+256 uses z[1],z[3],z[5],z[7] -> k=t+256+512m (j odd).
    float2 Z[8];
    {
        float pr=z[0].x+z[4].x, pi=z[0].y+z[4].y, mr=z[0].x-z[4].x, mi=z[0].y-z[4].y;
        float qr=z[2].x+z[6].x, qi=z[2].y+z[6].y, nr=z[2].x-z[6].x, ni=z[2].y-z[6].y;
        Z[0]=make_float2(pr+qr,pi+qi); Z[2]=make_float2(mr+ni,mi-nr);
        Z[4]=make_float2(pr-qr,pi-qi); Z[6]=make_float2(mr-ni,mi+nr);
    }
    {
        float pr=z[1].x+z[5].x, pi=z[1].y+z[5].y, mr=z[1].x-z[5].x, mi=z[1].y-z[5].y;
        float qr=z[3].x+z[7].x, qi=z[3].y+z[7].y, nr=z[3].x-z[7].x, ni=z[3].y-z[7].y;
        Z[1]=make_float2(pr+qr,pi+qi); Z[3]=make_float2(mr+ni,mi-nr);
        Z[5]=make_float2(pr-qr,pi-qi); Z[7]=make_float2(mr-ni,mi+nr);
    }
    // Z[j] = FFT(row0 + i*row1) at k = t + 256j, natural order. Publish once.
#pragma unroll
    for (int j = 0; j < 8; ++j) Lr[288*j] = Z[j];
    __syncthreads();

    // Untangle + LN moments. Repartition: thread t handles CONTIGUOUS
    // k in [4t,4t+4) and [1024+4t, 1024+4t+4) so the epilogue is float4.
    // Re X0[k] = (ReZ[k]+ReZ[N-k])/2, Re X1[k] = (ImZ[k]+ImZ[N-k])/2.
    float y0v[8], y1v[8];
    float s0=0.f, ss0=0.f, s1=0.f, ss1=0.f;
    const float2* const Ls = L + (4*t + (t >> 1));  // phys(4t+1024h+c) = base + 1152h + c
#pragma unroll
    for (int h = 0; h < 2; ++h) {
#pragma unroll
        for (int c = 0; c < 4; ++c) {
            const int k  = 4*t + 1024*h + c;
            const int rv = (CD - k) & (CD - 1);
            float2 zk = Ls[c + 1152*h];
            float2 zr = L[rv + (rv >> 3)];
            float a = 0.5f*(zk.x + zr.x);
            float b = 0.5f*(zk.y + zr.y);
            const int i = 4*h + c;
            y0v[i]=a; y1v[i]=b;
            s0+=a; ss0+=a*a; s1+=b; ss1+=b*b;
        }
    }

    // Wave-64 shuffle reduce, then cross-wave via rmem.
#pragma unroll
    for (int off = 32; off > 0; off >>= 1) {
        s0  += __shfl_down(s0,  off, 64);
        ss0 += __shfl_down(ss0, off, 64);
        s1  += __shfl_down(s1,  off, 64);
        ss1 += __shfl_down(ss1, off, 64);
    }
    const int wave = t >> 6;
    if ((t & 63) == 0) {
        rmem[4*wave+0]=s0; rmem[4*wave+1]=ss0; rmem[4*wave+2]=s1; rmem[4*wave+3]=ss1;
    }
    __syncthreads();
    if (t == 0) {
        float S0=0.f, SS0=0.f, S1=0.f, SS1=0.f;
#pragma unroll
        for (int w = 0; w < 4; ++w) {
            S0+=rmem[4*w+0]; SS0+=rmem[4*w+1]; S1+=rmem[4*w+2]; SS1+=rmem[4*w+3];
        }
        const float inv = 1.0f/(float)CD;
        float m0=S0*inv, m1=S1*inv;
        rmem[16]=m0; rmem[17]=rsqrtf(SS0*inv - m0*m0 + 1e-5f);
        rmem[18]=m1; rmem[19]=rsqrtf(SS1*inv - m1*m1 + 1e-5f);
    }
    __syncthreads();
    const float mu0=rmem[16], r0=rmem[17], mu1=rmem[18], r1=rmem[19];

    const float4* gv = (const float4*)gamma;
    const float4* bv = (const float4*)beta;
    float4* o0 = (float4*)(out + row0*CD);
    float4* o1 = (float4*)(out + (row0+1)*CD);
#pragma unroll
    for (int h = 0; h < 2; ++h) {
        const int i4 = t + 256*h;                  // float4 index: elements 4t+1024h..+3
        float4 g  = gv[i4];
        float4 be = bv[i4];
        float4 v0, v1;
        v0.x=(y0v[4*h+0]-mu0)*r0*g.x+be.x; v0.y=(y0v[4*h+1]-mu0)*r0*g.y+be.y;
        v0.z=(y0v[4*h+2]-mu0)*r0*g.z+be.z; v0.w=(y0v[4*h+3]-mu0)*r0*g.w+be.w;
        v1.x=(y1v[4*h+0]-mu1)*r1*g.x+be.x; v1.y=(y1v[4*h+1]-mu1)*r1*g.y+be.y;
        v1.z=(y1v[4*h+2]-mu1)*r1*g.z+be.z; v1.w=(y1v[4*h+3]-mu1)*r1*g.w+be.w;
        o0[i4]=v0; o1[i4]=v1;
    }
}

extern "C" void kernel_launch(void* const* d_in, const int* in_sizes, int n_in,
                              void* d_out, int out_size, void* d_ws, size_t ws_size,
                              hipStream_t stream) {
    (void)in_sizes; (void)n_in; (void)d_ws; (void)ws_size; (void)out_size;
    const float* x     = (const float*)d_in[0];
    const float* gamma = (const float*)d_in[1];
    const float* beta  = (const float*)d_in[2];
    float* out = (float*)d_out;

    const int total_rows = 4 * 4096;           // B * N
    const int blocks = total_rows / 2;         // one block per row pair
    fourier_ln_kernel<<<blocks, TPB, 0, stream>>>(x, gamma, beta, out);
}